// Round 9
// baseline (1306.896 us; speedup 1.0000x reference)
//
#include <hip/hip_runtime.h>
#include <cstdint>
#include <cstddef>

#define NB 16
#define NC 64
#define HW 4096
#define SLICE ((size_t)(NB*NC*HW))   // 4194304 floats per state
#define NSTEP 16
#define GRIDB 256

// ws layout (float offsets)
#define WS_WT    ((size_t)0)          // wT  [16][3][64 o][64 c] = 196608
#define WS_BV    ((size_t)196608)     // bvec[16][64]            = 1024
#define WS_SV    ((size_t)205824)     // sv  [16][3][64]         = 3072
#define WS_SVMU  ((size_t)208896)     // svmu[16][3][64]         = 3072
#define WS_BAR   ((size_t)211968)     // barrier cnt/gen (2 uints)

typedef _Float16 half8 __attribute__((ext_vector_type(8)));  // 8 f16 (4 VGPRs)
typedef float f32x4 __attribute__((ext_vector_type(4)));     // MFMA acc

// wT[b][g][o][c] = (lat @ Wk + bk) at j = o*192 + (g*64+c) ; bvec = lat @ Wb + bb
__global__ __launch_bounds__(256) void k_w(const float* __restrict__ lat,
    const float* __restrict__ Wk, const float* __restrict__ bk,
    const float* __restrict__ Wb, const float* __restrict__ bb,
    float* __restrict__ wT, float* __restrict__ bvec) {
  int t = threadIdx.x;
  if (blockIdx.x < 48) {
    int j = blockIdx.x*256 + t;
    float acc[16];
#pragma unroll
    for (int b = 0; b < 16; b++) acc[b] = 0.f;
#pragma unroll 4
    for (int k = 0; k < 512; k++) {
      float wv = Wk[(size_t)k*12288 + j];
#pragma unroll
      for (int b = 0; b < 16; b++) acc[b] = fmaf(lat[b*512 + k], wv, acc[b]);
    }
    int o = j / 192, cf = j % 192;
    int g = cf >> 6, c = cf & 63;
    float bkj = bk[j];
#pragma unroll
    for (int b = 0; b < 16; b++)
      wT[(((size_t)(b*3 + g))*64 + o)*64 + c] = acc[b] + bkj;
  } else if (t < 64) {
    int j = t;
    float acc[16];
#pragma unroll
    for (int b = 0; b < 16; b++) acc[b] = 0.f;
    for (int k = 0; k < 512; k++) {
      float wv = Wb[k*64 + j];
#pragma unroll
      for (int b = 0; b < 16; b++) acc[b] = fmaf(lat[b*512 + k], wv, acc[b]);
    }
    float bbj = bb[j];
#pragma unroll
    for (int b = 0; b < 16; b++) bvec[b*64 + j] = acc[b] + bbj;
  }
}

// embs slice 0 init + barrier reset
__global__ void k_init(float* __restrict__ e0, unsigned* __restrict__ bar) {
  if (blockIdx.x == 0 && threadIdx.x == 0) { bar[0] = 0u; bar[1] = 0u; }
  int idx4 = (blockIdx.x*256 + threadIdx.x) * 4;
  float4 v = make_float4(0.f, 0.f, 0.f, 0.f);
  if ((idx4 & 262143) == 2080) v.x = 1.0f;  // 32*64+32, channel 0
  *(float4*)(e0 + idx4) = v;
}

// ---- grid barrier (GRIDB blocks, cooperative launch) ----
__device__ __forceinline__ void gridbar(unsigned* bar) {
  __syncthreads();
  if (threadIdx.x == 0) {
    __threadfence();
    unsigned g = __hip_atomic_load(&bar[1], __ATOMIC_RELAXED, __HIP_MEMORY_SCOPE_AGENT);
    unsigned v = __hip_atomic_fetch_add(&bar[0], 1u, __ATOMIC_ACQ_REL, __HIP_MEMORY_SCOPE_AGENT);
    if (v == (unsigned)(GRIDB - 1)) {
      __hip_atomic_store(&bar[0], 0u, __ATOMIC_RELAXED, __HIP_MEMORY_SCOPE_AGENT);
      __hip_atomic_fetch_add(&bar[1], 1u, __ATOMIC_RELEASE, __HIP_MEMORY_SCOPE_AGENT);
    } else {
      while (__hip_atomic_load(&bar[1], __ATOMIC_ACQUIRE, __HIP_MEMORY_SCOPE_AGENT) == g)
        __builtin_amdgcn_s_sleep(1);
    }
    __threadfence();
  }
  __syncthreads();
}

struct SBC {
  alignas(16) _Float16 Bhi[2][6144];   // per group: [c8][px^c8][cj]
  alignas(16) _Float16 Blo[2][6144];
  alignas(16) _Float16 Whi[2][6144];   // per kc: [g][o][slot-swizzled c_rel]
  alignas(16) _Float16 Wlo[2][6144];
  float svL[192], svmuL[192], biasL[192], bvecL[64];
  float red[2][4][6];
};  // 101,056 B -> 1 block/CU (8 waves)

// stats for one (b,c): streaming separable sobel, neighbors via shfl. 256-thr group.
__device__ void statsOne(SBC& sh, int grp, int t8, int b, int c,
                         const float* __restrict__ st,
                         float* __restrict__ svb, float* __restrict__ svmub) {
  __syncthreads();   // red[] reuse across calls (block-wide, both groups in lockstep)
  const float* base = st + (size_t)(b*NC + c) * HW;
  int w = t8 & 63, wv = t8 >> 6, h0 = wv * 16;
  float s0=0,q0=0,s1=0,q1=0,s2=0,q2=0;
  float d_prev=0.f, s_prev=0.f, d_cur, s_cur, v_cur;
#define MKDS(X, D, S)                                  \
  {                                                    \
    float xl = __shfl((X), (w + 63) & 63);             \
    float xr = __shfl((X), (w + 1) & 63);              \
    if (w == 0)  xl = 0.f;                             \
    if (w == 63) xr = 0.f;                             \
    (D) = xr - xl; (S) = xl + 2.f*(X) + xr;            \
  }
  if (h0 > 0) {
    float x = base[(h0-1)*64 + w];
    MKDS(x, d_prev, s_prev)
  }
  {
    float x = base[h0*64 + w];
    MKDS(x, d_cur, s_cur)
    v_cur = x;
  }
#pragma unroll
  for (int k = 0; k < 16; k++) {
    int hn = h0 + k + 1;
    float d_nxt=0.f, s_nxt=0.f, v_nxt=0.f;
    if (hn < 64) {                  // wave-uniform
      float x = base[hn*64 + w];
      MKDS(x, d_nxt, s_nxt)
      v_nxt = x;
    }
    float gx = (d_prev + 2.f*d_cur + d_nxt) * 0.125f;
    float gy = (s_nxt - s_prev) * 0.125f;
    s0 += v_cur; q0 = fmaf(v_cur, v_cur, q0);
    s1 += gx;    q1 = fmaf(gx, gx, q1);
    s2 += gy;    q2 = fmaf(gy, gy, q2);
    d_prev = d_cur; s_prev = s_cur;
    d_cur = d_nxt; s_cur = s_nxt; v_cur = v_nxt;
  }
#undef MKDS
#pragma unroll
  for (int off = 32; off >= 1; off >>= 1) {
    s0 += __shfl_xor(s0, off); q0 += __shfl_xor(q0, off);
    s1 += __shfl_xor(s1, off); q1 += __shfl_xor(q1, off);
    s2 += __shfl_xor(s2, off); q2 += __shfl_xor(q2, off);
  }
  int lane = t8 & 63;
  if (lane == 0) {
    sh.red[grp][wv][0]=s0; sh.red[grp][wv][1]=q0; sh.red[grp][wv][2]=s1;
    sh.red[grp][wv][3]=q1; sh.red[grp][wv][4]=s2; sh.red[grp][wv][5]=q2;
  }
  __syncthreads();
  if (t8 == 0) {
    float r[6];
#pragma unroll
    for (int u = 0; u < 6; u++)
      r[u] = sh.red[grp][0][u]+sh.red[grp][1][u]+sh.red[grp][2][u]+sh.red[grp][3][u];
#pragma unroll
    for (int g = 0; g < 3; g++) {
      float mu  = r[2*g] * (1.f/HW);
      float var = fmaxf(r[2*g+1]*(1.f/HW) - mu*mu, 0.f);
      float sv  = 1.f / sqrtf(var + 1e-5f);
      svb  [b*192 + g*64 + c] = sv;
      svmub[b*192 + g*64 + c] = sv * mu;
    }
  }
}

// One step: stats (4 ch/block) -> gridbar -> fused GEMM (4 rows/block).
// 256 blocks x 512 thr (2 groups), cooperative.
__global__ __launch_bounds__(512, 2) void k_step(const float* __restrict__ st,
    float* __restrict__ stn, const float* __restrict__ wT,
    const float* __restrict__ bvec, float* __restrict__ svb,
    float* __restrict__ svmub, const float* __restrict__ leakp,
    float* __restrict__ out0, float* __restrict__ out2,
    unsigned* __restrict__ bar, int last) {
  __shared__ SBC sh;
  int bid = blockIdx.x, t = threadIdx.x;
  int grp = t >> 8, t8 = t & 255;
  int b = bid >> 4;

  // ---- stats phase: channels (bid&15)*4 + grp*2 + {0,1} ----
  int c0 = (bid & 15) * 4 + grp * 2;
  statsOne(sh, grp, t8, b, c0,     st, svb, svmub);
  statsOne(sh, grp, t8, b, c0 + 1, st, svb, svmub);
  gridbar(bar);

  // ---- fused phase ----
  int xcd = bid & 7, ii = (bid >> 3) & 1;
  int lane = t8 & 63, wt = t8 >> 6;
  const float* stb = st + (size_t)b*NC*HW;
  float leak = fminf(fmaxf(leakp[0], 0.001f), 1000.f);

  if (t < 192) { sh.svL[t] = svb[b*192 + t]; sh.svmuL[t] = svmub[b*192 + t]; }
  if (t < 64) sh.bvecL[t] = bvec[b*64 + t];
  __syncthreads();          // sv ready

  // stage scaled W (hi/lo f16) for BOTH kc + bias dot, once per block
  if (t < 192) {
    int g = t >> 6, o = t & 63;
    float biasacc = 0.f;
#pragma unroll
    for (int kc = 0; kc < 2; kc++) {
      const float* wrow = wT + (((size_t)(b*3 + g))*64 + o)*64 + kc*32;
#pragma unroll
      for (int s = 0; s < 4; s++) {
        float4 va = *(const float4*)(wrow + s*8);
        float4 vb4 = *(const float4*)(wrow + s*8 + 4);
        float wv[8] = {va.x,va.y,va.z,va.w,vb4.x,vb4.y,vb4.z,vb4.w};
        half8 hv, lv;
#pragma unroll
        for (int jj = 0; jj < 8; jj++) {
          int cg = g*64 + kc*32 + s*8 + jj;
          float scaled = wv[jj] * sh.svL[cg];
          biasacc = fmaf(wv[jj], sh.svmuL[cg], biasacc);
          _Float16 h = (_Float16)scaled;
          hv[jj] = h;
          lv[jj] = (_Float16)(scaled - (float)h);
        }
        int swz = (s ^ (o & 3) ^ ((o >> 2) & 3)) & 3;
        int sidx = (g*64 + o)*32 + (swz << 3);
        *(half8*)(&sh.Whi[kc][sidx]) = hv;
        *(half8*)(&sh.Wlo[kc][sidx]) = lv;
      }
    }
    sh.biasL[t] = biasacc;
  }

#define LOADW(KC, R, XW)                                                 \
  _Pragma("unroll")                                                      \
  for (int i = 0; i < 3; i++) {                                          \
    int u = t8 + i*256;                                                  \
    int c8 = u / 192, pxu = u % 192;                                     \
    int rho = pxu >> 6, ww = pxu & 63;                                   \
    int row = (R) - 1 + rho;                                             \
    bool ok = (row >= 0) && (row < 64);                                  \
    int rowc = ok ? row : 0;                                             \
    const float* gp = stb + (size_t)((KC)*32 + c8*8)*HW + rowc*64 + ww;  \
    _Pragma("unroll")                                                    \
    for (int ii2 = 0; ii2 < 8; ii2++) {                                  \
      float val = gp[(size_t)ii2*HW];                                    \
      XW[i][ii2] = ok ? val : 0.f;                                       \
    }                                                                    \
  }

#define PACKW(XW)                                                        \
  _Pragma("unroll")                                                      \
  for (int i = 0; i < 3; i++) {                                          \
    int u = t8 + i*256;                                                  \
    int c8 = u / 192, pxu = u % 192;                                     \
    half8 hv, lv;                                                        \
    _Pragma("unroll")                                                    \
    for (int ii2 = 0; ii2 < 8; ii2++) {                                  \
      float x = XW[i][ii2];                                              \
      _Float16 h = (_Float16)x;                                          \
      hv[ii2] = h;                                                       \
      lv[ii2] = (_Float16)(x - (float)h);                                \
    }                                                                    \
    int di = (c8*192 + (pxu ^ c8)) * 8;                                  \
    *(half8*)(&sh.Bhi[grp][di]) = hv;                                    \
    *(half8*)(&sh.Blo[grp][di]) = lv;                                    \
  }

#define MFMAS(KC)                                                        \
  {                                                                      \
    half8 ahi[3], alo[3];                                                \
    int oa = wt*16 + (lane & 15);                                        \
    int c4 = lane >> 4;                                                  \
    int slotx = (c4 ^ (oa & 3) ^ ((oa >> 2) & 3)) & 3;                   \
    _Pragma("unroll")                                                    \
    for (int g = 0; g < 3; g++) {                                        \
      int sidx = (g*64 + oa)*32 + (slotx << 3);                          \
      ahi[g] = *(const half8*)(&sh.Whi[KC][sidx]);                       \
      alo[g] = *(const half8*)(&sh.Wlo[KC][sidx]);                       \
    }                                                                    \
    _Pragma("unroll")                                                    \
    for (int n = 0; n < 12; n++) {                                       \
      int px = n*16 + (lane & 15);                                       \
      int bidx = (c4*192 + (px ^ c4))*8;                                 \
      half8 bh = *(const half8*)(&sh.Bhi[grp][bidx]);                    \
      half8 bl = *(const half8*)(&sh.Blo[grp][bidx]);                    \
      accB[n] = __builtin_amdgcn_mfma_f32_16x16x32_f16(ahi[1], bh, accB[n], 0,0,0); \
      accB[n] = __builtin_amdgcn_mfma_f32_16x16x32_f16(ahi[1], bl, accB[n], 0,0,0); \
      accB[n] = __builtin_amdgcn_mfma_f32_16x16x32_f16(alo[1], bh, accB[n], 0,0,0); \
      accC[n] = __builtin_amdgcn_mfma_f32_16x16x32_f16(ahi[2], bh, accC[n], 0,0,0); \
      accC[n] = __builtin_amdgcn_mfma_f32_16x16x32_f16(ahi[2], bl, accC[n], 0,0,0); \
      accC[n] = __builtin_amdgcn_mfma_f32_16x16x32_f16(alo[2], bh, accC[n], 0,0,0); \
      if (n >= 4 && n < 8) {                                             \
        accA[n-4] = __builtin_amdgcn_mfma_f32_16x16x32_f16(ahi[0], bh, accA[n-4], 0,0,0); \
        accA[n-4] = __builtin_amdgcn_mfma_f32_16x16x32_f16(ahi[0], bl, accA[n-4], 0,0,0); \
        accA[n-4] = __builtin_amdgcn_mfma_f32_16x16x32_f16(alo[0], bh, accA[n-4], 0,0,0); \
      }                                                                  \
    }                                                                    \
  }

#pragma unroll
  for (int rr = 0; rr < 2; rr++) {
    int r = xcd*8 + ii*4 + grp*2 + rr;
    f32x4 accA[4] = {}; f32x4 accB[12] = {}; f32x4 accC[12] = {};
    float xw0[3][8], xw1[3][8];

    LOADW(0, r, xw0)
    __syncthreads();        // iter0: W/bias ready; iter1: prior B reads done
    PACKW(xw0)
    __syncthreads();        // kc0 planes ready
    LOADW(1, r, xw1)        // prefetch kc1 under kc0 MFMAs
    MFMAS(0)
    __syncthreads();        // kc0 B reads done
    PACKW(xw1)
    __syncthreads();        // kc1 planes ready
    MFMAS(1)

    // epilogue: in-register sobel on mixed images + bias + residual
#pragma unroll
    for (int j = 0; j < 4; j++) {
      int o = wt*16 + ((lane >> 4) << 2) + j;
      float Sx[4], Sy[4];
#pragma unroll
      for (int nc = 0; nc < 4; nc++) {
        Sx[nc] = accB[nc][j] + 2.f*accB[4+nc][j] + accB[8+nc][j];
        Sy[nc] = accC[8+nc][j] - accC[nc][j];
      }
      float bt = sh.bvecL[o] - sh.biasL[o] - sh.biasL[64+o] - sh.biasL[128+o];
#pragma unroll
      for (int nc = 0; nc < 4; nc++) {
        int nm = (nc > 0) ? nc-1 : 0;
        int np = (nc < 3) ? nc+1 : 3;
        float xl1 = __shfl(Sx[nc], (lane - 1) & 63);
        float xl2 = (nc > 0) ? __shfl(Sx[nm], (lane + 15) & 63) : 0.f;
        float xL  = (lane & 15) ? xl1 : xl2;
        float xr1 = __shfl(Sx[nc], (lane + 1) & 63);
        float xr2 = (nc < 3) ? __shfl(Sx[np], (lane - 15) & 63) : 0.f;
        float xR  = ((lane & 15) == 15) ? xr2 : xr1;
        float yl1 = __shfl(Sy[nc], (lane - 1) & 63);
        float yl2 = (nc > 0) ? __shfl(Sy[nm], (lane + 15) & 63) : 0.f;
        float yL  = (lane & 15) ? yl1 : yl2;
        float yr1 = __shfl(Sy[nc], (lane + 1) & 63);
        float yr2 = (nc < 3) ? __shfl(Sy[np], (lane - 15) & 63) : 0.f;
        float yR  = ((lane & 15) == 15) ? yr2 : yr1;
        float gx = (xR - xL) * 0.125f;
        float gy = (yL + 2.f*Sy[nc] + yR) * 0.125f;
        float nw = accA[nc][j] + gx + gy + bt;
        int wpx = nc*16 + (lane & 15);
        size_t gi = (size_t)(b*NC + o)*HW + (size_t)r*64 + wpx;
        float nv = st[gi] + leak * nw;
        stn[gi] = nv;
        if (last && o < 3) {
          size_t oi = (size_t)(b*3 + o)*HW + (size_t)r*64 + wpx;
          out2[oi] = nv;
          out0[oi] = fminf(fmaxf(nv, -1.f), 1.f);
        }
      }
    }
  }
#undef LOADW
#undef PACKW
#undef MFMAS
}

extern "C" void kernel_launch(void* const* d_in, const int* in_sizes, int n_in,
                              void* d_out, int out_size, void* d_ws, size_t ws_size,
                              hipStream_t stream) {
  const float* lat   = (const float*)d_in[0];
  const float* Wk    = (const float*)d_in[1];
  const float* bk    = (const float*)d_in[2];
  const float* Wb    = (const float*)d_in[3];
  const float* bb    = (const float*)d_in[4];
  const float* leakp = (const float*)d_in[5];
  float* out = (float*)d_out;
  float* ws  = (float*)d_ws;
  float* wT    = ws + WS_WT;
  float* bvec  = ws + WS_BV;
  float* svbuf = ws + WS_SV;
  float* svmub = ws + WS_SVMU;
  unsigned* bar = (unsigned*)(ws + WS_BAR);
  float* out0 = out;
  float* embs = out + 196608;
  float* out2 = out + 196608 + 17*SLICE;

  hipLaunchKernelGGL(k_w,    dim3(49),   dim3(256), 0, stream, lat, Wk, bk, Wb, bb, wT, bvec);
  hipLaunchKernelGGL(k_init, dim3(4096), dim3(256), 0, stream, embs, bar);
  for (int tstep = 0; tstep < NSTEP; tstep++) {
    const float* stc = embs + (size_t)tstep*SLICE;
    float*       stn = embs + (size_t)(tstep+1)*SLICE;
    int last = (tstep == NSTEP-1);
    void* args[] = { (void*)&stc, (void*)&stn, (void*)&wT, (void*)&bvec,
                     (void*)&svbuf, (void*)&svmub, (void*)&leakp,
                     (void*)&out0, (void*)&out2, (void*)&bar, (void*)&last };
    hipLaunchCooperativeKernel((void*)k_step, dim3(GRIDB), dim3(512),
                               args, 0, stream);
  }
}

// Round 10
// 910.286 us; speedup vs baseline: 1.4357x; 1.4357x over previous
//
#include <hip/hip_runtime.h>
#include <cstdint>
#include <cstddef>

#define NB 16
#define NC 64
#define HW 4096
#define SLICE ((size_t)(NB*NC*HW))   // 4194304 floats per state
#define NSTEP 16

// ws layout (float offsets)
#define WS_WT    ((size_t)0)          // wT  [16][3][64 o][64 c] = 196608
#define WS_BV    ((size_t)196608)     // bvec[16][64]            = 1024
#define WS_STATS ((size_t)197632)     // 3 bufs x [16][3][64][2] = 3*6144

typedef _Float16 half8 __attribute__((ext_vector_type(8)));  // 8 f16 (4 VGPRs)
typedef float f32x4 __attribute__((ext_vector_type(4)));     // MFMA acc

// wT[b][g][o][c] = (lat @ Wk + bk) at j = o*192 + (g*64+c) ; bvec = lat @ Wb + bb
__global__ __launch_bounds__(256) void k_w(const float* __restrict__ lat,
    const float* __restrict__ Wk, const float* __restrict__ bk,
    const float* __restrict__ Wb, const float* __restrict__ bb,
    float* __restrict__ wT, float* __restrict__ bvec) {
  int t = threadIdx.x;
  if (blockIdx.x < 48) {
    int j = blockIdx.x*256 + t;
    float acc[16];
#pragma unroll
    for (int b = 0; b < 16; b++) acc[b] = 0.f;
#pragma unroll 4
    for (int k = 0; k < 512; k++) {
      float wv = Wk[(size_t)k*12288 + j];
#pragma unroll
      for (int b = 0; b < 16; b++) acc[b] = fmaf(lat[b*512 + k], wv, acc[b]);
    }
    int o = j / 192, cf = j % 192;
    int g = cf >> 6, c = cf & 63;
    float bkj = bk[j];
#pragma unroll
    for (int b = 0; b < 16; b++)
      wT[(((size_t)(b*3 + g))*64 + o)*64 + c] = acc[b] + bkj;
  } else if (t < 64) {
    int j = t;
    float acc[16];
#pragma unroll
    for (int b = 0; b < 16; b++) acc[b] = 0.f;
    for (int k = 0; k < 512; k++) {
      float wv = Wb[k*64 + j];
#pragma unroll
      for (int b = 0; b < 16; b++) acc[b] = fmaf(lat[b*512 + k], wv, acc[b]);
    }
    float bbj = bb[j];
#pragma unroll
    for (int b = 0; b < 16; b++) bvec[b*64 + j] = acc[b] + bbj;
  }
}

// embs slice 0 init + zero stats buf1 (write target of step 0)
__global__ void k_init(float* __restrict__ e0, float* __restrict__ buf1) {
  int bid = blockIdx.x, t = threadIdx.x;
  if (bid == 0) {
#pragma unroll
    for (int i = 0; i < 24; i++) buf1[i*256 + t] = 0.f;
  }
  int idx4 = (bid*256 + t) * 4;
  float4 v = make_float4(0.f, 0.f, 0.f, 0.f);
  if ((idx4 & 262143) == 2080) v.x = 1.0f;  // 32*64+32, channel 0
  *(float4*)(e0 + idx4) = v;
}

// step-0 stats: raw sums (s,q) of v, gx, gy per (b,c) -> buf0
__global__ __launch_bounds__(256) void k_stats0(const float* __restrict__ st,
    float* __restrict__ sbuf) {
  int c = blockIdx.x, b = blockIdx.y, t = threadIdx.x;
  __shared__ float red[4][6];
  const float* base = st + (size_t)(b*NC + c) * HW;
  int w = t & 63, wv = t >> 6, h0 = wv * 16;
  float s0=0,q0=0,s1=0,q1=0,s2=0,q2=0;
  float d_prev=0.f, s_prev=0.f, d_cur, s_cur, v_cur;
#define MKDS(X, D, S)                                  \
  {                                                    \
    float xl = __shfl((X), (w + 63) & 63);             \
    float xr = __shfl((X), (w + 1) & 63);              \
    if (w == 0)  xl = 0.f;                             \
    if (w == 63) xr = 0.f;                             \
    (D) = xr - xl; (S) = xl + 2.f*(X) + xr;            \
  }
  if (h0 > 0) {
    float x = base[(h0-1)*64 + w];
    MKDS(x, d_prev, s_prev)
  }
  {
    float x = base[h0*64 + w];
    MKDS(x, d_cur, s_cur)
    v_cur = x;
  }
#pragma unroll
  for (int k = 0; k < 16; k++) {
    int hn = h0 + k + 1;
    float d_nxt=0.f, s_nxt=0.f, v_nxt=0.f;
    if (hn < 64) {
      float x = base[hn*64 + w];
      MKDS(x, d_nxt, s_nxt)
      v_nxt = x;
    }
    float gx = (d_prev + 2.f*d_cur + d_nxt) * 0.125f;
    float gy = (s_nxt - s_prev) * 0.125f;
    s0 += v_cur; q0 = fmaf(v_cur, v_cur, q0);
    s1 += gx;    q1 = fmaf(gx, gx, q1);
    s2 += gy;    q2 = fmaf(gy, gy, q2);
    d_prev = d_cur; s_prev = s_cur;
    d_cur = d_nxt; s_cur = s_nxt; v_cur = v_nxt;
  }
#undef MKDS
#pragma unroll
  for (int off = 32; off >= 1; off >>= 1) {
    s0 += __shfl_xor(s0, off); q0 += __shfl_xor(q0, off);
    s1 += __shfl_xor(s1, off); q1 += __shfl_xor(q1, off);
    s2 += __shfl_xor(s2, off); q2 += __shfl_xor(q2, off);
  }
  int lane = t & 63;
  if (lane == 0) {
    red[wv][0]=s0; red[wv][1]=q0; red[wv][2]=s1;
    red[wv][3]=q1; red[wv][4]=s2; red[wv][5]=q2;
  }
  __syncthreads();
  if (t == 0) {
    float r[6];
#pragma unroll
    for (int u = 0; u < 6; u++) r[u] = red[0][u]+red[1][u]+red[2][u]+red[3][u];
#pragma unroll
    for (int g = 0; g < 3; g++) {
      size_t base2 = ((size_t)(b*3 + g)*64 + c)*2;
      sbuf[base2]     = r[2*g];
      sbuf[base2 + 1] = r[2*g + 1];
    }
  }
}

struct SB2 {
  alignas(16) _Float16 Bhi[6144];      // [c8][px^c8][cj] (per row,kc staging)
  alignas(16) _Float16 Blo[6144];
  alignas(16) _Float16 Whi[2][6144];   // [kc][g][o][slot-swizzled c_rel]
  alignas(16) _Float16 Wlo[2][6144];
  float svL[192], svmuL[192], biasL[192], bvecL[64];
};  // 76288 B -> 2 blocks/CU

// One step, fully fused: sv/svmu from raw sums -> mix GEMM for rows r0-1..r0+2
// (2 owned + 2 halo) -> residual write (owned) -> stats of NEW state (owned rows)
// accumulated by atomics into statsW for the next step.
__global__ __launch_bounds__(256, 2) void k_step(const float* __restrict__ st,
    float* __restrict__ stn, const float* __restrict__ wT,
    const float* __restrict__ bvec, const float* __restrict__ statsR,
    float* __restrict__ statsW, float* __restrict__ statsZ,
    const float* __restrict__ leakp,
    float* __restrict__ out0, float* __restrict__ out2, int last) {
  __shared__ SB2 sh;
  int bid = blockIdx.x, t = threadIdx.x;
  int b = bid >> 5;
  int r0 = (bid & 7) * 8 + ((bid >> 3) & 3) * 2;   // XCD-banded rows
  int lane = t & 63, wt = t >> 6;
  const float* stb = st + (size_t)b*NC*HW;
  float leak = fminf(fmaxf(leakp[0], 0.001f), 1000.f);

  // zero the t+2 stats buffer: 6144 floats / 512 blocks = 12 each
  if (t < 12) statsZ[bid*12 + t] = 0.f;

  // prelude: raw sums -> sv, sv*mu
  if (t < 192) {
    float s = statsR[(b*192 + t)*2];
    float q = statsR[(b*192 + t)*2 + 1];
    float mu = s * (1.f/HW);
    float var = fmaxf(q*(1.f/HW) - mu*mu, 0.f);
    float sv = 1.f / sqrtf(var + 1e-5f);
    sh.svL[t] = sv; sh.svmuL[t] = sv * mu;
  }
  if (t < 64) sh.bvecL[t] = bvec[b*64 + t];
  __syncthreads();          // sv ready

  // stage scaled W (hi/lo f16) for BOTH kc + bias dot, once per block
  if (t < 192) {
    int g = t >> 6, o = t & 63;
    float biasacc = 0.f;
#pragma unroll
    for (int kc = 0; kc < 2; kc++) {
      const float* wrow = wT + (((size_t)(b*3 + g))*64 + o)*64 + kc*32;
#pragma unroll
      for (int s = 0; s < 4; s++) {
        float4 va = *(const float4*)(wrow + s*8);
        float4 vb4 = *(const float4*)(wrow + s*8 + 4);
        float wv[8] = {va.x,va.y,va.z,va.w,vb4.x,vb4.y,vb4.z,vb4.w};
        half8 hv, lv;
#pragma unroll
        for (int jj = 0; jj < 8; jj++) {
          int cg = g*64 + kc*32 + s*8 + jj;
          float scaled = wv[jj] * sh.svL[cg];
          biasacc = fmaf(wv[jj], sh.svmuL[cg], biasacc);
          _Float16 h = (_Float16)scaled;
          hv[jj] = h;
          lv[jj] = (_Float16)(scaled - (float)h);
        }
        int swz = (s ^ (o & 3) ^ ((o >> 2) & 3)) & 3;
        int sidx = (g*64 + o)*32 + (swz << 3);
        *(half8*)(&sh.Whi[kc][sidx]) = hv;
        *(half8*)(&sh.Wlo[kc][sidx]) = lv;
      }
    }
    sh.biasL[t] = biasacc;
  }

#define LOADW(KC, R, XW)                                                 \
  _Pragma("unroll")                                                      \
  for (int i = 0; i < 3; i++) {                                          \
    int u = t + i*256;                                                   \
    int c8 = u / 192, pxu = u % 192;                                     \
    int rho = pxu >> 6, ww = pxu & 63;                                   \
    int row = (R) - 1 + rho;                                             \
    bool ok = (row >= 0) && (row < 64);                                  \
    int rowc = ok ? row : 0;                                             \
    const float* gp = stb + (size_t)((KC)*32 + c8*8)*HW + rowc*64 + ww;  \
    _Pragma("unroll")                                                    \
    for (int e8 = 0; e8 < 8; e8++) {                                     \
      float val = gp[(size_t)e8*HW];                                     \
      XW[i][e8] = ok ? val : 0.f;                                        \
    }                                                                    \
  }

#define PACKW(XW)                                                        \
  _Pragma("unroll")                                                      \
  for (int i = 0; i < 3; i++) {                                          \
    int u = t + i*256;                                                   \
    int c8 = u / 192, pxu = u % 192;                                     \
    half8 hv, lv;                                                        \
    _Pragma("unroll")                                                    \
    for (int e8 = 0; e8 < 8; e8++) {                                     \
      float x = XW[i][e8];                                               \
      _Float16 h = (_Float16)x;                                          \
      hv[e8] = h;                                                        \
      lv[e8] = (_Float16)(x - (float)h);                                 \
    }                                                                    \
    int di = (c8*192 + (pxu ^ c8)) * 8;                                  \
    *(half8*)(sh.Bhi + di) = hv;                                         \
    *(half8*)(sh.Blo + di) = lv;                                         \
  }

#define MFMAS(KC)                                                        \
  {                                                                      \
    half8 ahi[3], alo[3];                                                \
    int oa = wt*16 + (lane & 15);                                        \
    int c4 = lane >> 4;                                                  \
    int slotx = (c4 ^ (oa & 3) ^ ((oa >> 2) & 3)) & 3;                   \
    _Pragma("unroll")                                                    \
    for (int g = 0; g < 3; g++) {                                        \
      int sidx = (g*64 + oa)*32 + (slotx << 3);                          \
      ahi[g] = *(const half8*)(&sh.Whi[KC][sidx]);                       \
      alo[g] = *(const half8*)(&sh.Wlo[KC][sidx]);                       \
    }                                                                    \
    _Pragma("unroll")                                                    \
    for (int n = 0; n < 12; n++) {                                       \
      int px = n*16 + (lane & 15);                                       \
      int bidx = (c4*192 + (px ^ c4))*8;                                 \
      half8 bh = *(const half8*)(sh.Bhi + bidx);                         \
      half8 bl = *(const half8*)(sh.Blo + bidx);                         \
      accB[n] = __builtin_amdgcn_mfma_f32_16x16x32_f16(ahi[1], bh, accB[n], 0,0,0); \
      accB[n] = __builtin_amdgcn_mfma_f32_16x16x32_f16(ahi[1], bl, accB[n], 0,0,0); \
      accB[n] = __builtin_amdgcn_mfma_f32_16x16x32_f16(alo[1], bh, accB[n], 0,0,0); \
      accC[n] = __builtin_amdgcn_mfma_f32_16x16x32_f16(ahi[2], bh, accC[n], 0,0,0); \
      accC[n] = __builtin_amdgcn_mfma_f32_16x16x32_f16(ahi[2], bl, accC[n], 0,0,0); \
      accC[n] = __builtin_amdgcn_mfma_f32_16x16x32_f16(alo[2], bh, accC[n], 0,0,0); \
      if (n >= 4 && n < 8) {                                             \
        accA[n-4] = __builtin_amdgcn_mfma_f32_16x16x32_f16(ahi[0], bh, accA[n-4], 0,0,0); \
        accA[n-4] = __builtin_amdgcn_mfma_f32_16x16x32_f16(ahi[0], bl, accA[n-4], 0,0,0); \
        accA[n-4] = __builtin_amdgcn_mfma_f32_16x16x32_f16(alo[0], bh, accA[n-4], 0,0,0); \
      }                                                                  \
    }                                                                    \
  }

  float nv4[4][16];   // new-state values for rows r0-1 .. r0+2 (16 px/thread)

#pragma unroll
  for (int rr = 0; rr < 4; rr++) {
    int r = r0 - 1 + rr;
    if (r >= 0 && r < 64) {          // block-uniform
      f32x4 accA[4] = {}; f32x4 accB[12] = {}; f32x4 accC[12] = {};
      float xw0[3][8], xw1[3][8];

      LOADW(0, r, xw0)
      __syncthreads();        // first: W/bias ready; later: prior B reads done
      PACKW(xw0)
      __syncthreads();        // kc0 planes ready
      LOADW(1, r, xw1)        // prefetch kc1 under kc0 MFMAs
      MFMAS(0)
      __syncthreads();        // kc0 B reads done
      PACKW(xw1)
      __syncthreads();        // kc1 planes ready
      MFMAS(1)

      // epilogue: sobel on mixed images + bias + residual -> nv
#pragma unroll
      for (int j = 0; j < 4; j++) {
        int o = wt*16 + ((lane >> 4) << 2) + j;
        float Sx[4], Sy[4];
#pragma unroll
        for (int nc = 0; nc < 4; nc++) {
          Sx[nc] = accB[nc][j] + 2.f*accB[4+nc][j] + accB[8+nc][j];
          Sy[nc] = accC[8+nc][j] - accC[nc][j];
        }
        float bt = sh.bvecL[o] - sh.biasL[o] - sh.biasL[64+o] - sh.biasL[128+o];
#pragma unroll
        for (int nc = 0; nc < 4; nc++) {
          int nm = (nc > 0) ? nc-1 : 0;
          int np = (nc < 3) ? nc+1 : 3;
          float xl1 = __shfl(Sx[nc], (lane - 1) & 63);
          float xl2 = (nc > 0) ? __shfl(Sx[nm], (lane + 15) & 63) : 0.f;
          float xL  = (lane & 15) ? xl1 : xl2;
          float xr1 = __shfl(Sx[nc], (lane + 1) & 63);
          float xr2 = (nc < 3) ? __shfl(Sx[np], (lane - 15) & 63) : 0.f;
          float xR  = ((lane & 15) == 15) ? xr2 : xr1;
          float yl1 = __shfl(Sy[nc], (lane - 1) & 63);
          float yl2 = (nc > 0) ? __shfl(Sy[nm], (lane + 15) & 63) : 0.f;
          float yL  = (lane & 15) ? yl1 : yl2;
          float yr1 = __shfl(Sy[nc], (lane + 1) & 63);
          float yr2 = (nc < 3) ? __shfl(Sy[np], (lane - 15) & 63) : 0.f;
          float yR  = ((lane & 15) == 15) ? yr2 : yr1;
          float gx = (xR - xL) * 0.125f;
          float gy = (yL + 2.f*Sy[nc] + yR) * 0.125f;
          float nw = accA[nc][j] + gx + gy + bt;
          int wpx = nc*16 + (lane & 15);
          size_t gi = (size_t)(b*NC + o)*HW + (size_t)r*64 + wpx;
          float nv = st[gi] + leak * nw;
          nv4[rr][j*4 + nc] = nv;
          if (rr == 1 || rr == 2) {
            stn[gi] = nv;
            if (last && o < 3) {
              size_t oi = (size_t)(b*3 + o)*HW + (size_t)r*64 + wpx;
              out2[oi] = nv;
              out0[oi] = fminf(fmaxf(nv, -1.f), 1.f);
            }
          }
        }
      }
    } else {
#pragma unroll
      for (int u = 0; u < 16; u++) nv4[rr][u] = 0.f;
    }
  }
#undef LOADW
#undef PACKW
#undef MFMAS

  // ---- stats of NEW state (owned rows) for the next step ----
  if (!last) {
#pragma unroll
    for (int j = 0; j < 4; j++) {
      float dxv[4][4], sxv[4][4];
#pragma unroll
      for (int rw = 0; rw < 4; rw++) {
        float vv[4];
#pragma unroll
        for (int nc = 0; nc < 4; nc++) vv[nc] = nv4[rw][j*4 + nc];
#pragma unroll
        for (int nc = 0; nc < 4; nc++) {
          int nm = (nc > 0) ? nc-1 : 0;
          int np = (nc < 3) ? nc+1 : 3;
          float xl1 = __shfl(vv[nc], (lane - 1) & 63);
          float xl2 = (nc > 0) ? __shfl(vv[nm], (lane + 15) & 63) : 0.f;
          float xL  = (lane & 15) ? xl1 : xl2;
          float xr1 = __shfl(vv[nc], (lane + 1) & 63);
          float xr2 = (nc < 3) ? __shfl(vv[np], (lane - 15) & 63) : 0.f;
          float xR  = ((lane & 15) == 15) ? xr2 : xr1;
          dxv[rw][nc] = xR - xL;
          sxv[rw][nc] = xL + 2.f*vv[nc] + xR;
        }
      }
      float s0=0,q0=0,s1=0,q1=0,s2=0,q2=0;
#pragma unroll
      for (int rr = 1; rr <= 2; rr++) {
#pragma unroll
        for (int nc = 0; nc < 4; nc++) {
          float v = nv4[rr][j*4 + nc];
          s0 += v; q0 = fmaf(v, v, q0);
          float gx = (dxv[rr-1][nc] + 2.f*dxv[rr][nc] + dxv[rr+1][nc]) * 0.125f;
          float gy = (sxv[rr+1][nc] - sxv[rr-1][nc]) * 0.125f;
          s1 += gx; q1 = fmaf(gx, gx, q1);
          s2 += gy; q2 = fmaf(gy, gy, q2);
        }
      }
#pragma unroll
      for (int m = 1; m <= 8; m <<= 1) {
        s0 += __shfl_xor(s0, m); q0 += __shfl_xor(q0, m);
        s1 += __shfl_xor(s1, m); q1 += __shfl_xor(q1, m);
        s2 += __shfl_xor(s2, m); q2 += __shfl_xor(q2, m);
      }
      if ((lane & 15) == 0) {
        int o = wt*16 + ((lane >> 4) << 2) + j;
        atomicAdd(&statsW[((size_t)(b*3 + 0)*64 + o)*2    ], s0);
        atomicAdd(&statsW[((size_t)(b*3 + 0)*64 + o)*2 + 1], q0);
        atomicAdd(&statsW[((size_t)(b*3 + 1)*64 + o)*2    ], s1);
        atomicAdd(&statsW[((size_t)(b*3 + 1)*64 + o)*2 + 1], q1);
        atomicAdd(&statsW[((size_t)(b*3 + 2)*64 + o)*2    ], s2);
        atomicAdd(&statsW[((size_t)(b*3 + 2)*64 + o)*2 + 1], q2);
      }
    }
  }
}

extern "C" void kernel_launch(void* const* d_in, const int* in_sizes, int n_in,
                              void* d_out, int out_size, void* d_ws, size_t ws_size,
                              hipStream_t stream) {
  const float* lat   = (const float*)d_in[0];
  const float* Wk    = (const float*)d_in[1];
  const float* bk    = (const float*)d_in[2];
  const float* Wb    = (const float*)d_in[3];
  const float* bb    = (const float*)d_in[4];
  const float* leakp = (const float*)d_in[5];
  float* out = (float*)d_out;
  float* ws  = (float*)d_ws;
  float* wT    = ws + WS_WT;
  float* bvec  = ws + WS_BV;
  float* sb0   = ws + WS_STATS;
  float* sb1   = ws + WS_STATS + 6144;
  float* sb2   = ws + WS_STATS + 12288;
  float* sbuf[3] = { sb0, sb1, sb2 };
  float* out0 = out;
  float* embs = out + 196608;
  float* out2 = out + 196608 + 17*SLICE;

  hipLaunchKernelGGL(k_w,      dim3(49),     dim3(256), 0, stream, lat, Wk, bk, Wb, bb, wT, bvec);
  hipLaunchKernelGGL(k_init,   dim3(4096),   dim3(256), 0, stream, embs, sb1);
  hipLaunchKernelGGL(k_stats0, dim3(64,16),  dim3(256), 0, stream, embs, sb0);
  for (int tstep = 0; tstep < NSTEP; tstep++) {
    const float* stc = embs + (size_t)tstep*SLICE;
    float*       stn = embs + (size_t)(tstep+1)*SLICE;
    hipLaunchKernelGGL(k_step, dim3(512), dim3(256), 0, stream,
                       stc, stn, wT, bvec,
                       sbuf[tstep % 3], sbuf[(tstep+1) % 3], sbuf[(tstep+2) % 3],
                       leakp, out0, out2, (int)(tstep == NSTEP-1));
  }
}

// Round 11
// 600.401 us; speedup vs baseline: 2.1767x; 1.5161x over previous
//
#include <hip/hip_runtime.h>
#include <cstdint>
#include <cstddef>

#define NB 16
#define NC 64
#define HW 4096
#define SLICE ((size_t)(NB*NC*HW))   // 4194304 floats per state
#define NSTEP 16

// ws layout (float offsets)
#define WS_WT    ((size_t)0)          // wT  [16][3][64 o][64 c] = 196608
#define WS_BV    ((size_t)196608)     // bvec[16][64]            = 1024
#define WS_SV    ((size_t)197632)     // sv  [16][3][64]         = 3072
#define WS_SVMU  ((size_t)200704)     // svmu[16][3][64]         = 3072
#define WS_PLA   ((size_t)203776)     // planes A: 4194304 floats (16 MB)
#define WS_PLB   ((size_t)4398080)    // planes B: 4194304 floats
// end = 8592384 floats = 34.4 MB (<= R1's proven ws usage)

typedef _Float16 half8 __attribute__((ext_vector_type(8)));  // 8 f16 (4 VGPRs)
typedef float f32x4 __attribute__((ext_vector_type(4)));     // MFMA acc

// wT[b][g][o][c] = (lat @ Wk + bk) at j = o*192 + (g*64+c) ; bvec = lat @ Wb + bb
__global__ __launch_bounds__(256) void k_w(const float* __restrict__ lat,
    const float* __restrict__ Wk, const float* __restrict__ bk,
    const float* __restrict__ Wb, const float* __restrict__ bb,
    float* __restrict__ wT, float* __restrict__ bvec) {
  int t = threadIdx.x;
  if (blockIdx.x < 48) {
    int j = blockIdx.x*256 + t;
    float acc[16];
#pragma unroll
    for (int b = 0; b < 16; b++) acc[b] = 0.f;
#pragma unroll 4
    for (int k = 0; k < 512; k++) {
      float wv = Wk[(size_t)k*12288 + j];
#pragma unroll
      for (int b = 0; b < 16; b++) acc[b] = fmaf(lat[b*512 + k], wv, acc[b]);
    }
    int o = j / 192, cf = j % 192;
    int g = cf >> 6, c = cf & 63;
    float bkj = bk[j];
#pragma unroll
    for (int b = 0; b < 16; b++)
      wT[(((size_t)(b*3 + g))*64 + o)*64 + c] = acc[b] + bkj;
  } else if (t < 64) {
    int j = t;
    float acc[16];
#pragma unroll
    for (int b = 0; b < 16; b++) acc[b] = 0.f;
    for (int k = 0; k < 512; k++) {
      float wv = Wb[k*64 + j];
#pragma unroll
      for (int b = 0; b < 16; b++) acc[b] = fmaf(lat[b*512 + k], wv, acc[b]);
    }
    float bbj = bb[j];
#pragma unroll
    for (int b = 0; b < 16; b++) bvec[b*64 + j] = acc[b] + bbj;
  }
}

// embs slice 0 + initial packed planes (delta at [b][ch0][32][32])
__global__ void k_init(float* __restrict__ e0, float* __restrict__ plA) {
  int f4 = blockIdx.x*256 + threadIdx.x;
  float4 v = make_float4(0.f, 0.f, 0.f, 0.f);
  if (f4 < 1048576) {
    if ((f4 & 65535) == 520) v.x = 1.0f;            // float idx b*262144+2080
    *(float4*)(e0 + (size_t)f4*4) = v;
  } else {
    int g4 = f4 - 1048576;
    if ((g4 & 65535) == 2080)                        // half idx b*524288+16640
      v.x = __uint_as_float(0x00003C00u);            // half pair (1.0h, 0)
    *(float4*)(plA + (size_t)g4*4) = v;
  }
}

// per (b,c): moments of st, gx, gy via separable sobel; 18 upfront loads.
__global__ __launch_bounds__(256) void k_stats(const float* __restrict__ st,
    float* __restrict__ svb, float* __restrict__ svmub) {
  int c = blockIdx.x, b = blockIdx.y, t = threadIdx.x;
  __shared__ float red[4][6];
  const float* base = st + (size_t)(b*NC + c) * HW;
  int w = t & 63, wv = t >> 6, h0 = wv * 16;
  float x[18];
#pragma unroll
  for (int i = 0; i < 18; i++) {
    int row = h0 - 1 + i;
    x[i] = (row >= 0 && row < 64) ? base[row*64 + w] : 0.f;
  }
  float d[18], s[18];
#pragma unroll
  for (int i = 0; i < 18; i++) {
    float xl = __shfl(x[i], (w + 63) & 63);
    float xr = __shfl(x[i], (w + 1) & 63);
    if (w == 0)  xl = 0.f;
    if (w == 63) xr = 0.f;
    d[i] = xr - xl; s[i] = xl + 2.f*x[i] + xr;
  }
  float s0=0,q0=0,s1=0,q1=0,s2=0,q2=0;
#pragma unroll
  for (int k = 0; k < 16; k++) {
    float v  = x[k+1];
    float gx = (d[k] + 2.f*d[k+1] + d[k+2]) * 0.125f;
    float gy = (s[k+2] - s[k]) * 0.125f;
    s0 += v;  q0 = fmaf(v, v, q0);
    s1 += gx; q1 = fmaf(gx, gx, q1);
    s2 += gy; q2 = fmaf(gy, gy, q2);
  }
#pragma unroll
  for (int off = 32; off >= 1; off >>= 1) {
    s0 += __shfl_xor(s0, off); q0 += __shfl_xor(q0, off);
    s1 += __shfl_xor(s1, off); q1 += __shfl_xor(q1, off);
    s2 += __shfl_xor(s2, off); q2 += __shfl_xor(q2, off);
  }
  int lane = t & 63;
  if (lane == 0) {
    red[wv][0]=s0; red[wv][1]=q0; red[wv][2]=s1;
    red[wv][3]=q1; red[wv][4]=s2; red[wv][5]=q2;
  }
  __syncthreads();
  if (t == 0) {
    float r[6];
#pragma unroll
    for (int u = 0; u < 6; u++) r[u] = red[0][u]+red[1][u]+red[2][u]+red[3][u];
#pragma unroll
    for (int g = 0; g < 3; g++) {
      float mu  = r[2*g] * (1.f/HW);
      float var = fmaxf(r[2*g+1]*(1.f/HW) - mu*mu, 0.f);
      float sv  = 1.f / sqrtf(var + 1e-5f);
      svb  [b*192 + g*64 + c] = sv;
      svmub[b*192 + g*64 + c] = sv * mu;
    }
  }
}

struct SG {
  alignas(16) _Float16 Bwin[32768];   // [pl 2][c8 8][px 256][cj 8] = 64 KB
  float biasL[64];
};  // 64.3 KB -> 2 blocks/CU

// GEMM via pre-packed planes: stage 4-row window (copy), W frags in registers,
// MFMA, sobel-after-mix epilogue, residual write, pack next-step planes.
__global__ __launch_bounds__(256, 2) void k_gemm(const float* __restrict__ st,
    float* __restrict__ stn, const float* __restrict__ wT,
    const float* __restrict__ bvec, const float* __restrict__ svb,
    const float* __restrict__ svmub, const _Float16* __restrict__ plR,
    _Float16* __restrict__ plW, const float* __restrict__ leakp,
    float* __restrict__ out0, float* __restrict__ out2, int last) {
  __shared__ SG sh;
  int bid = blockIdx.x, t = threadIdx.x;
  int b = bid >> 5;
  int r0 = ((((bid & 7) << 2) | ((bid >> 3) & 3))) << 1;   // XCD row banding
  int lane = t & 63, wt = t >> 6, c4 = lane >> 4;
  float leak = fminf(fmaxf(leakp[0], 0.001f), 1000.f);

  // ---- stage B window: 4096 16B units, contiguous global -> linear LDS ----
  const _Float16* plb = plR + (size_t)b*524288;
#pragma unroll
  for (int i = 0; i < 16; i++) {
    int u = t + i*256;
    int pl = u >> 11, rest = u & 2047;          // rest = c8*256 + pxl
    int pxg = (r0 - 1)*64 + (rest & 255);
    int pxc = pxg < 0 ? 0 : (pxg > 4095 ? 4095 : pxg);
    const _Float16* gp = plb + ((size_t)pl*8 + (rest >> 8))*32768 + (size_t)pxc*8;
    float4 v = *(const float4*)gp;
    if (pxg < 0 || pxg > 4095) v = make_float4(0.f,0.f,0.f,0.f);
    *(float4*)(sh.Bwin + (size_t)u*8) = v;
  }

  // ---- W fragments (scaled, hi/lo) in registers + bias ----
  int oa = wt*16 + (lane & 15);
  half8 whi[3][2], wlo[3][2];
  float biasacc = 0.f;
#pragma unroll
  for (int g = 0; g < 3; g++) {
#pragma unroll
    for (int kc = 0; kc < 2; kc++) {
      const float* wrow = wT + (((size_t)(b*3 + g))*64 + oa)*64 + kc*32 + c4*8;
      const float* svp  = svb   + b*192 + g*64 + kc*32 + c4*8;
      const float* svmp = svmub + b*192 + g*64 + kc*32 + c4*8;
      float4 wa = *(const float4*)wrow;  float4 wb2 = *(const float4*)(wrow + 4);
      float4 sa = *(const float4*)svp;   float4 sb2 = *(const float4*)(svp + 4);
      float4 ma = *(const float4*)svmp;  float4 mb2 = *(const float4*)(svmp + 4);
      float wv[8] = {wa.x,wa.y,wa.z,wa.w, wb2.x,wb2.y,wb2.z,wb2.w};
      float sv[8] = {sa.x,sa.y,sa.z,sa.w, sb2.x,sb2.y,sb2.z,sb2.w};
      float mv[8] = {ma.x,ma.y,ma.z,ma.w, mb2.x,mb2.y,mb2.z,mb2.w};
      half8 hv, lv;
#pragma unroll
      for (int jj = 0; jj < 8; jj++) {
        float scaled = wv[jj] * sv[jj];
        biasacc = fmaf(wv[jj], mv[jj], biasacc);
        _Float16 h = (_Float16)scaled;
        hv[jj] = h;
        lv[jj] = (_Float16)(scaled - (float)h);
      }
      whi[g][kc] = hv; wlo[g][kc] = lv;
    }
  }
  biasacc += __shfl_xor(biasacc, 16);
  biasacc += __shfl_xor(biasacc, 32);
  if (c4 == 0) sh.biasL[oa] = bvec[b*64 + oa] - biasacc;
  __syncthreads();    // window + bias ready; only barrier in kernel

#pragma unroll
  for (int rr = 0; rr < 2; rr++) {
    int r = r0 + rr;
    f32x4 accA[4] = {}; f32x4 accB[12] = {}; f32x4 accC[12] = {};
#pragma unroll
    for (int kc = 0; kc < 2; kc++) {
#pragma unroll
      for (int n = 0; n < 12; n++) {
        int pxl = rr*64 + n*16 + (lane & 15);
        half8 bh = *(const half8*)(sh.Bwin + ((size_t)(     kc*4 + c4)*256 + pxl)*8);
        half8 bl = *(const half8*)(sh.Bwin + ((size_t)(8 +  kc*4 + c4)*256 + pxl)*8);
        accB[n] = __builtin_amdgcn_mfma_f32_16x16x32_f16(whi[1][kc], bh, accB[n], 0,0,0);
        accB[n] = __builtin_amdgcn_mfma_f32_16x16x32_f16(whi[1][kc], bl, accB[n], 0,0,0);
        accB[n] = __builtin_amdgcn_mfma_f32_16x16x32_f16(wlo[1][kc], bh, accB[n], 0,0,0);
        accC[n] = __builtin_amdgcn_mfma_f32_16x16x32_f16(whi[2][kc], bh, accC[n], 0,0,0);
        accC[n] = __builtin_amdgcn_mfma_f32_16x16x32_f16(whi[2][kc], bl, accC[n], 0,0,0);
        accC[n] = __builtin_amdgcn_mfma_f32_16x16x32_f16(wlo[2][kc], bh, accC[n], 0,0,0);
        if (n >= 4 && n < 8) {
          accA[n-4] = __builtin_amdgcn_mfma_f32_16x16x32_f16(whi[0][kc], bh, accA[n-4], 0,0,0);
          accA[n-4] = __builtin_amdgcn_mfma_f32_16x16x32_f16(whi[0][kc], bl, accA[n-4], 0,0,0);
          accA[n-4] = __builtin_amdgcn_mfma_f32_16x16x32_f16(wlo[0][kc], bh, accA[n-4], 0,0,0);
        }
      }
    }

    // ---- epilogue: in-register sobel on mixed images + bias + residual ----
    float nv16[16];
#pragma unroll
    for (int j = 0; j < 4; j++) {
      int o = wt*16 + (c4 << 2) + j;
      float Sx[4], Sy[4];
#pragma unroll
      for (int nc = 0; nc < 4; nc++) {
        Sx[nc] = accB[nc][j] + 2.f*accB[4+nc][j] + accB[8+nc][j];
        Sy[nc] = accC[8+nc][j] - accC[nc][j];
      }
      float bt = sh.biasL[o];
#pragma unroll
      for (int nc = 0; nc < 4; nc++) {
        int nm = (nc > 0) ? nc-1 : 0;
        int np = (nc < 3) ? nc+1 : 3;
        float xl1 = __shfl(Sx[nc], (lane - 1) & 63);
        float xl2 = (nc > 0) ? __shfl(Sx[nm], (lane + 15) & 63) : 0.f;
        float xL  = (lane & 15) ? xl1 : xl2;
        float xr1 = __shfl(Sx[nc], (lane + 1) & 63);
        float xr2 = (nc < 3) ? __shfl(Sx[np], (lane - 15) & 63) : 0.f;
        float xR  = ((lane & 15) == 15) ? xr2 : xr1;
        float yl1 = __shfl(Sy[nc], (lane - 1) & 63);
        float yl2 = (nc > 0) ? __shfl(Sy[nm], (lane + 15) & 63) : 0.f;
        float yL  = (lane & 15) ? yl1 : yl2;
        float yr1 = __shfl(Sy[nc], (lane + 1) & 63);
        float yr2 = (nc < 3) ? __shfl(Sy[np], (lane - 15) & 63) : 0.f;
        float yR  = ((lane & 15) == 15) ? yr2 : yr1;
        float gx = (xR - xL) * 0.125f;
        float gy = (yL + 2.f*Sy[nc] + yR) * 0.125f;
        float nw = accA[nc][j] + gx + gy + bt;
        int wpx = nc*16 + (lane & 15);
        size_t gi = (size_t)(b*NC + o)*HW + (size_t)r*64 + wpx;
        float nvv = st[gi] + leak * nw;
        stn[gi] = nvv;
        nv16[j*4 + nc] = nvv;
        if (last && o < 3) {
          size_t oi = (size_t)(b*3 + o)*HW + (size_t)r*64 + wpx;
          out2[oi] = nvv;
          out0[oi] = fminf(fmaxf(nvv, -1.f), 1.f);
        }
      }
    }

    // ---- pack nv -> next-step planes (skip on last step) ----
    if (!last) {
      int pl = c4 & 1;                 // 0 = hi plane, 1 = lo plane
      int g8 = wt*2 + (c4 >> 1);       // 8-channel group
      _Float16* pw = plW + (size_t)b*524288 + ((size_t)pl*8 + g8)*32768;
#pragma unroll
      for (int nc = 0; nc < 4; nc++) {
        float own[4], rcv[4];
#pragma unroll
        for (int j = 0; j < 4; j++) {
          own[j] = nv16[j*4 + nc];
          rcv[j] = __shfl_xor(own[j], 16);
        }
        float xx[8];
#pragma unroll
        for (int jj = 0; jj < 8; jj++)
          xx[jj] = ((jj >> 2) == (c4 & 1)) ? own[jj & 3] : rcv[jj & 3];
        half8 v8;
        if (pl == 0) {
#pragma unroll
          for (int jj = 0; jj < 8; jj++) v8[jj] = (_Float16)xx[jj];
        } else {
#pragma unroll
          for (int jj = 0; jj < 8; jj++) {
            _Float16 h = (_Float16)xx[jj];
            v8[jj] = (_Float16)(xx[jj] - (float)h);
          }
        }
        int gpx = r*64 + nc*16 + (lane & 15);
        *(half8*)(pw + (size_t)gpx*8) = v8;
      }
    }
  }
}

extern "C" void kernel_launch(void* const* d_in, const int* in_sizes, int n_in,
                              void* d_out, int out_size, void* d_ws, size_t ws_size,
                              hipStream_t stream) {
  const float* lat   = (const float*)d_in[0];
  const float* Wk    = (const float*)d_in[1];
  const float* bk    = (const float*)d_in[2];
  const float* Wb    = (const float*)d_in[3];
  const float* bb    = (const float*)d_in[4];
  const float* leakp = (const float*)d_in[5];
  float* out = (float*)d_out;
  float* ws  = (float*)d_ws;
  float* wT    = ws + WS_WT;
  float* bvec  = ws + WS_BV;
  float* svbuf = ws + WS_SV;
  float* svmub = ws + WS_SVMU;
  _Float16* plbuf[2] = { (_Float16*)(ws + WS_PLA), (_Float16*)(ws + WS_PLB) };
  float* out0 = out;
  float* embs = out + 196608;
  float* out2 = out + 196608 + 17*SLICE;

  hipLaunchKernelGGL(k_w,    dim3(49),   dim3(256), 0, stream, lat, Wk, bk, Wb, bb, wT, bvec);
  hipLaunchKernelGGL(k_init, dim3(8192), dim3(256), 0, stream, embs, ws + WS_PLA);
  for (int tstep = 0; tstep < NSTEP; tstep++) {
    const float* stc = embs + (size_t)tstep*SLICE;
    float*       stn = embs + (size_t)(tstep+1)*SLICE;
    hipLaunchKernelGGL(k_stats, dim3(64,16), dim3(256), 0, stream, stc, svbuf, svmub);
    hipLaunchKernelGGL(k_gemm, dim3(512), dim3(256), 0, stream,
                       stc, stn, wT, bvec, svbuf, svmub,
                       plbuf[tstep & 1], plbuf[(tstep+1) & 1], leakp,
                       out0, out2, (int)(tstep == NSTEP-1));
  }
}